// Round 6
// baseline (414.652 us; speedup 1.0000x reference)
//
#include <hip/hip_runtime.h>

// Frequency-domain room sim, 3-kernel phase split.
//   SF = DFT(sound_field) per cell (unnormalized); per block b:
//     T = clip(res,0,1) * (SF + DFT(env_b));  mic_b = IDFT(T[mic])/1024;
//     SF = box3x3x3(T)   (pointwise per bin -> recursion independent per bin)
// P1: env FFTs (2 real cells per complex FFT, both FFTs of a 4-cell WG in ONE
//     float4 LDS buffer -> ds_read_b128), direct uint4 stores of (b,bin,cell)
//     fp16 spectra. XCD-chunked blockIdx swizzle for L2 write merging.
// P2: 513 WGs (bin k = row k, bin 512 needs no special case). Register-lean:
//     SF + T (reused as Z then Y) + EB/TB dbuf = 128 array VGPRs, no spills.
//     y-sum & interior x-sum via wave shuffles; cross-wave x rows via a small
//     double-buffered LDS edge buffer -> 1 barrier per block-iter.
// P3: 16 inverse FFTs of the mic spectra.

#define NFFT   1024
#define NF     513
#define NKP    257
#define NCELLS 4096
#define MICQ   136      // x*16+y = 8*16+8
#define PI2    6.28318530717958647692f

// float4-granular LDS skew: <=2-way for strides {1,4,16,64,256} and bitrev
__device__ __forceinline__ int IDX4(int i) { return i + (i >> 3) + (i >> 6); }

__device__ __forceinline__ float clip01(float v) { return fminf(fmaxf(v, 0.0f), 1.0f); }
__device__ __forceinline__ unsigned pkh2(float a, float b) {
    union { _Float16 h[2]; unsigned u; } z;
    z.h[0] = (_Float16)a; z.h[1] = (_Float16)b;
    return z.u;
}
__device__ __forceinline__ float h2lo(unsigned u) {
    union { unsigned u; _Float16 h[2]; } z; z.u = u; return (float)z.h[0];
}
__device__ __forceinline__ float h2hi(unsigned u) {
    union { unsigned u; _Float16 h[2]; } z; z.u = u; return (float)z.h[1];
}
__device__ __forceinline__ unsigned cmp4(const uint4& v, int c) {
    return c == 0 ? v.x : c == 1 ? v.y : c == 2 ? v.z : v.w;
}
__device__ __forceinline__ float f4c(const float4& v, int c) {
    return c == 0 ? v.x : c == 1 ? v.y : c == 2 ? v.z : v.w;
}
__device__ __forceinline__ float4 f4add(float4 a, float4 b) {
    return make_float4(a.x + b.x, a.y + b.y, a.z + b.z, a.w + b.w);
}
__device__ __forceinline__ float4 f4sub(float4 a, float4 b) {
    return make_float4(a.x - b.x, a.y - b.y, a.z - b.z, a.w - b.w);
}
// complex multiply on (.x,.y) and (.z,.w) by twiddle w
__device__ __forceinline__ float4 cmul2(float4 d, float2 w) {
    return make_float4(d.x * w.x - d.y * w.y, d.x * w.y + d.y * w.x,
                       d.z * w.x - d.w * w.y, d.z * w.y + d.w * w.x);
}
__device__ __forceinline__ float2 shfl2(float2 v, int srcLane) {
    return make_float2(__shfl(v.x, srcLane, 64), __shfl(v.y, srcLane, 64));
}

// ---------------- P1 ----------------
// WG = (block b, 4 cells); two packed real-pair FFTs in one float4 buffer.
__global__ __launch_bounds__(256) void k_p1(
    const float* __restrict__ tf, const float* __restrict__ imp,
    const float* __restrict__ noise, unsigned* __restrict__ Et,
    unsigned* __restrict__ TFt)
{
    __shared__ float4 FD[1168];        // IDX4(1023)=1165

    const int tid = threadIdx.x;
    // XCD-chunked swizzle: consecutive work on one XCD -> L2 write merging
    const int bid = blockIdx.x;
    const int w   = ((bid & 7) << 11) | (bid >> 3);
    const int b   = w >> 10;
    const int c0  = (w & 1023) << 2;

    // per-thread twiddles for the 5 fused (2x radix-2) DIF passes
    float2 tu0[5], tu1[5], tl[5];
    #pragma unroll
    for (int p = 0; p < 5; ++p) {
        const int lgU = 9 - 2 * p, lgL = lgU - 1, LL = 1 << lgL;
        const int j = tid & (LL - 1);
        const int iu0 = j << (9 - lgU), iu1 = (j + LL) << (9 - lgU), il = j << (9 - lgL);
        float s, c;
        __sincosf(-PI2 * (1.0f / 1024.0f) * (float)iu0, &s, &c); tu0[p] = make_float2(c, s);
        __sincosf(-PI2 * (1.0f / 1024.0f) * (float)iu1, &s, &c); tu1[p] = make_float2(c, s);
        __sincosf(-PI2 * (1.0f / 1024.0f) * (float)il,  &s, &c); tl[p]  = make_float2(c, s);
    }

    // env = clip(interp(imp),0,1)*noise for 4 cells; FFT0=(c0,c0+1), FFT1=(c0+2,c0+3)
    {
        const float* ipr = imp + ((size_t)b * NCELLS + c0) * 16;
        const float4 nz0 = *(const float4*)(noise + ((size_t)b * NCELLS + c0 + 0) * NFFT + 4 * tid);
        const float4 nz1 = *(const float4*)(noise + ((size_t)b * NCELLS + c0 + 1) * NFFT + 4 * tid);
        const float4 nz2 = *(const float4*)(noise + ((size_t)b * NCELLS + c0 + 2) * NFFT + 4 * tid);
        const float4 nz3 = *(const float4*)(noise + ((size_t)b * NCELLS + c0 + 3) * NFFT + 4 * tid);
        #pragma unroll
        for (int c = 0; c < 4; ++c) {
            int n = 4 * tid + c;
            float coord = (n + 0.5f) * (16.0f / 1024.0f) - 0.5f;
            coord = fminf(fmaxf(coord, 0.0f), 15.0f);
            int lo = (int)coord;
            int hi = lo + 1 > 15 ? 15 : lo + 1;
            float wl = coord - (float)lo, wh = 1.0f - wl;
            float e0 = clip01(ipr[lo]      * wh + ipr[hi]      * wl) * f4c(nz0, c);
            float e1 = clip01(ipr[16 + lo] * wh + ipr[16 + hi] * wl) * f4c(nz1, c);
            float e2 = clip01(ipr[32 + lo] * wh + ipr[32 + hi] * wl) * f4c(nz2, c);
            float e3 = clip01(ipr[48 + lo] * wh + ipr[48 + hi] * wl) * f4c(nz3, c);
            FD[IDX4(n)] = make_float4(e0, e1, e2, e3);
        }
    }
    __syncthreads();

    // forward FFT: 10 radix-2 DIF stages, fused 2/pass; both FFTs per b128 op
    #pragma unroll
    for (int p = 0; p < 5; ++p) {
        const int lgU = 9 - 2 * p, lgL = lgU - 1, LL = 1 << lgL;
        const int j = tid & (LL - 1), g = tid >> lgL;
        const int base = (g << (lgL + 2)) + j;
        const int q0 = IDX4(base), q1 = IDX4(base + LL);
        const int q2 = IDX4(base + 2 * LL), q3 = IDX4(base + 3 * LL);
        const float2 w0 = tu0[p], w1 = tu1[p], wl = tl[p];
        float4 a0 = FD[q0], a1 = FD[q1], a2 = FD[q2], a3 = FD[q3];
        float4 u0 = f4add(a0, a2), d0 = f4sub(a0, a2);
        float4 u2 = cmul2(d0, w0);
        float4 u1 = f4add(a1, a3), d1 = f4sub(a1, a3);
        float4 u3 = cmul2(d1, w1);
        FD[q0] = f4add(u0, u1);
        FD[q1] = cmul2(f4sub(u0, u1), wl);
        FD[q2] = f4add(u2, u3);
        FD[q3] = cmul2(f4sub(u2, u3), wl);
        __syncthreads();
    }

    // split packed spectra -> direct uint4 stores (4 cells per bin line)
    #pragma unroll
    for (int it = 0; it < 3; ++it) {
        int kq = tid + it * 256;
        if (kq < NF) {
            int s  = IDX4(__brev(kq) >> 22);
            int s2 = IDX4(__brev((1024 - kq) & 1023) >> 22);
            float4 F = FD[s], G = FD[s2];
            float a0r = 0.5f * (F.x + G.x), a0i = 0.5f * (F.y - G.y);
            float b0r = 0.5f * (F.y + G.y), b0i = 0.5f * (G.x - F.x);
            float a1r = 0.5f * (F.z + G.z), a1i = 0.5f * (F.w - G.w);
            float b1r = 0.5f * (F.w + G.w), b1i = 0.5f * (G.z - F.z);
            uint4 u = { pkh2(a0r, a0i), pkh2(b0r, b0i), pkh2(a1r, a1i), pkh2(b1r, b1i) };
            *(uint4*)(Et + ((size_t)b * NF + kq) * NCELLS + c0) = u;
        }
    }

    // tf: clip + pack bin pairs, direct uint4 store per kp
    {
        const float* r0 = tf + ((size_t)b * NCELLS + c0 + 0) * NF;
        const float* r1 = r0 + NF;
        const float* r2 = r1 + NF;
        const float* r3 = r2 + NF;
        for (int kp = tid; kp < NKP; kp += 256) {
            bool hv = kp < 256;
            uint4 u;
            u.x = pkh2(clip01(r0[2 * kp]), hv ? clip01(r0[2 * kp + 1]) : 0.0f);
            u.y = pkh2(clip01(r1[2 * kp]), hv ? clip01(r1[2 * kp + 1]) : 0.0f);
            u.z = pkh2(clip01(r2[2 * kp]), hv ? clip01(r2[2 * kp + 1]) : 0.0f);
            u.w = pkh2(clip01(r3[2 * kp]), hv ? clip01(r3[2 * kp + 1]) : 0.0f);
            *(uint4*)(TFt + ((size_t)b * NKP + kp) * NCELLS + c0) = u;
        }
    }
}

// ---------------- P2 ----------------
// Grid 513, one WG per bin. Thread q owns z-column of (x,y) = (q>>4, q&15).
// y-sum: wave shuffles (y spans one 16-lane group). x-sum: shuffles for
// interior, LDS edge buffer (double-buffered, 1 barrier/iter) across waves.
__global__ __launch_bounds__(256) void k_p2(
    const unsigned* __restrict__ Et, const unsigned* __restrict__ TFt,
    float2* __restrict__ ms)
{
    __shared__ float2 ebuf[2][2176];   // [dbuf][(edge-row*16+y)*17+z], 8 rows

    const int q    = threadIdx.x;
    const int k    = blockIdx.x;
    const int kp   = k >> 1, sel = k & 1;
    const int x    = q >> 4, y = q & 15;
    const int lane = q & 63, wv = q >> 6;   // x = 4*wv + ((q>>4)&3)
    const int xm3  = x & 3;

    float2 SF[16];
    #pragma unroll
    for (int z = 0; z < 16; ++z) SF[z] = make_float2(0.f, 0.f);

    uint4 EB[2][4], TB[2][4];
    {
        const uint4* ep = (const uint4*)(Et + (size_t)k * NCELLS + (q << 4));
        const uint4* tp = (const uint4*)(TFt + (size_t)kp * NCELLS + (q << 4));
        EB[0][0] = ep[0]; EB[0][1] = ep[1]; EB[0][2] = ep[2]; EB[0][3] = ep[3];
        TB[0][0] = tp[0]; TB[0][1] = tp[1]; TB[0][2] = tp[2]; TB[0][3] = tp[3];
    }

    #pragma unroll
    for (int b = 0; b < 16; ++b) {
        const int cur = b & 1, nxt = cur ^ 1;
        if (b + 1 < 16) {
            const uint4* ep = (const uint4*)(Et + ((size_t)(b + 1) * NF + k) * NCELLS + (q << 4));
            const uint4* tp = (const uint4*)(TFt + ((size_t)(b + 1) * NKP + kp) * NCELLS + (q << 4));
            EB[nxt][0] = ep[0]; EB[nxt][1] = ep[1]; EB[nxt][2] = ep[2]; EB[nxt][3] = ep[3];
            TB[nxt][0] = tp[0]; TB[nxt][1] = tp[1]; TB[nxt][2] = tp[2]; TB[nxt][3] = tp[3];
        }

        // T = r * (SF + E)
        float2 T[16];
        #pragma unroll
        for (int z = 0; z < 16; ++z) {
            unsigned eu = cmp4(EB[cur][z >> 2], z & 3);
            unsigned tu = cmp4(TB[cur][z >> 2], z & 3);
            float r = sel ? h2hi(tu) : h2lo(tu);
            T[z] = make_float2(r * (SF[z].x + h2lo(eu)),
                               r * (SF[z].y + h2hi(eu)));
        }
        if (q == MICQ) ms[b * NF + k] = T[8];

        // z-sum in place (rolling prev)
        {
            float2 p = make_float2(0.f, 0.f);
            #pragma unroll
            for (int z = 0; z < 16; ++z) {
                float2 c = T[z];
                float2 s = make_float2(c.x + p.x, c.y + p.y);
                if (z < 15) { s.x += T[z + 1].x; s.y += T[z + 1].y; }
                T[z] = s;
                p = c;
            }
        }

        // y-sum via shuffles (y fully inside a 16-lane group)
        #pragma unroll
        for (int z = 0; z < 16; ++z) {
            float2 v = T[z];
            float2 l = shfl2(v, lane - 1);
            float2 r = shfl2(v, lane + 1);
            float2 s = v;
            if (y > 0)  { s.x += l.x; s.y += l.y; }
            if (y < 15) { s.x += r.x; s.y += r.y; }
            T[z] = s;
        }

        // edge rows (x%4==0 and x%4==3) -> LDS for cross-wave x exchange
        {
            float2* eb = ebuf[cur];
            if (xm3 == 0) {
                #pragma unroll
                for (int z = 0; z < 16; ++z) eb[((2 * wv) * 16 + y) * 17 + z] = T[z];
            } else if (xm3 == 3) {
                #pragma unroll
                for (int z = 0; z < 16; ++z) eb[((2 * wv + 1) * 16 + y) * 17 + z] = T[z];
            }
        }
        __syncthreads();

        // x-sum: interior via shuffles, wave edges via LDS
        {
            const float2* eb = ebuf[cur];
            const int rm = (2 * wv - 1) < 0 ? 0 : (2 * wv - 1);
            const int rp = (2 * wv + 2) > 7 ? 7 : (2 * wv + 2);
            #pragma unroll
            for (int z = 0; z < 16; ++z) {
                float2 v = T[z];
                float2 lm = shfl2(v, lane - 16);
                float2 lp = shfl2(v, lane + 16);
                float2 s = v;
                if (x > 0) {
                    float2 u = (xm3 == 0) ? eb[(rm * 16 + y) * 17 + z] : lm;
                    s.x += u.x; s.y += u.y;
                }
                if (x < 15) {
                    float2 u = (xm3 == 3) ? eb[(rp * 16 + y) * 17 + z] : lp;
                    s.x += u.x; s.y += u.y;
                }
                SF[z] = s;
            }
        }
        // no trailing barrier: next iter writes the other ebuf half
    }
}

// ---------------- P3 ----------------
__device__ __forceinline__ int pd(int i) { return i + (i >> 5); }

__global__ __launch_bounds__(256) void k_p3(
    const float2* __restrict__ ms, float* __restrict__ out)
{
    __shared__ float2 FD[1056];
    const int b = blockIdx.x, tid = threadIdx.x;

    for (int j = tid; j < NFFT; j += 256) {
        int jj = (j <= 512) ? j : 1024 - j;
        float2 v = ms[b * NF + jj];
        if (j > 512) v.y = -v.y;
        FD[pd(__brev(j) >> 22)] = v;
    }
    __syncthreads();

    for (int lg = 0; lg <= 9; ++lg) {
        const int len = 1 << lg;
        for (int pr = tid; pr < 512; pr += 256) {
            const int jj = pr & (len - 1);
            const int i0 = ((pr >> lg) << (lg + 1)) + jj;
            const int i1 = i0 + len;
            const int iw = jj << (9 - lg);
            float sn, cs;
            __sincosf(-PI2 * (1.0f / 1024.0f) * (float)iw, &sn, &cs);
            float2 a = FD[pd(i0)], bb = FD[pd(i1)];
            float tr = bb.x * cs + bb.y * sn;
            float ti = bb.y * cs - bb.x * sn;
            FD[pd(i0)] = make_float2(a.x + tr, a.y + ti);
            FD[pd(i1)] = make_float2(a.x - tr, a.y - ti);
        }
        __syncthreads();
    }
    for (int t = tid; t < NFFT; t += 256)
        out[b * NFFT + t] = FD[pd(t)].x * (1.0f / 1024.0f);
}

extern "C" void kernel_launch(void* const* d_in, const int* in_sizes, int n_in,
                              void* d_out, int out_size, void* d_ws, size_t ws_size,
                              hipStream_t stream)
{
    const float* tf    = (const float*)d_in[1];
    const float* imp   = (const float*)d_in[2];
    const float* noise = (const float*)d_in[3];
    float* out = (float*)d_out;

    unsigned* Et  = (unsigned*)d_ws;                             // 16*513*4096 u32
    unsigned* TFt = Et + (size_t)16 * NF * NCELLS;               // 16*257*4096 u32
    float2*   ms  = (float2*)(TFt + (size_t)16 * NKP * NCELLS);  // 16*513 c64

    k_p1<<<16 * 1024, 256, 0, stream>>>(tf, imp, noise, Et, TFt);
    k_p2<<<NF, 256, 0, stream>>>(Et, TFt, ms);
    k_p3<<<16, 256, 0, stream>>>(ms, out);
}

// Round 8
// 388.687 us; speedup vs baseline: 1.0668x; 1.0668x over previous
//
#include <hip/hip_runtime.h>

// Frequency-domain room sim, 3-kernel phase split.
//   SF = DFT(sound_field) per cell (unnormalized); per block b:
//     T = clip(res,0,1) * (SF + DFT(env_b));  mic_b = IDFT(T[mic])/1024;
//     SF = box3x3x3(T)   (pointwise per bin -> recursion independent per bin)
// P1: env FFTs, 8 cells/WG as two packed float4 buffers (2 real cells per
//     complex lane-pair). Output = RAW packed spectrum in SLOT (bit-reversed)
//     order -> extract is a linear LDS read + fp16 pack + 16B coalesced store.
//     fp16 is safe here: |E| <= 1024 << 65504.
// P2: one WG per bin k (513). Reads slot rows brev(k) and brev(1024-k),
//     conj-split in registers, 16-block recursion in fp32 registers.
//     Box: z in regs; y/x via FP32 float2 LDS ping-pong (fp16 here was the
//     round-7 NaN: recursion state grows ~27x/block, overflows fp16).
// P3: 16 inverse FFTs of the mic spectra.

#define NFFT   1024
#define NF     513
#define NKP    257
#define NCELLS 4096
#define NPAIR  2048
#define MICQ   136      // x*16+y = 8*16+8
#define PI2    6.28318530717958647692f

// float4-granular LDS skew
__device__ __forceinline__ int IDX4(int i) { return i + (i >> 3) + (i >> 6); }

__device__ __forceinline__ float clip01(float v) { return fminf(fmaxf(v, 0.0f), 1.0f); }
__device__ __forceinline__ unsigned pkh2(float a, float b) {
    union { _Float16 h[2]; unsigned u; } z;
    z.h[0] = (_Float16)a; z.h[1] = (_Float16)b;
    return z.u;
}
__device__ __forceinline__ float h2lo(unsigned u) {
    union { unsigned u; _Float16 h[2]; } z; z.u = u; return (float)z.h[0];
}
__device__ __forceinline__ float h2hi(unsigned u) {
    union { unsigned u; _Float16 h[2]; } z; z.u = u; return (float)z.h[1];
}
__device__ __forceinline__ unsigned cmp4(const uint4& v, int c) {
    return c == 0 ? v.x : c == 1 ? v.y : c == 2 ? v.z : v.w;
}
__device__ __forceinline__ float f4c(const float4& v, int c) {
    return c == 0 ? v.x : c == 1 ? v.y : c == 2 ? v.z : v.w;
}
__device__ __forceinline__ float4 f4add(float4 a, float4 b) {
    return make_float4(a.x + b.x, a.y + b.y, a.z + b.z, a.w + b.w);
}
__device__ __forceinline__ float4 f4sub(float4 a, float4 b) {
    return make_float4(a.x - b.x, a.y - b.y, a.z - b.z, a.w - b.w);
}
__device__ __forceinline__ float4 cmul2(float4 d, float2 w) {
    return make_float4(d.x * w.x - d.y * w.y, d.x * w.y + d.y * w.x,
                       d.z * w.x - d.w * w.y, d.z * w.y + d.w * w.x);
}

// ---------------- P1 ----------------
// WG = (block b, 8 cells); two float4 FFT buffers, one barrier per fused pass.
// Grid 8192.
__global__ __launch_bounds__(256) void k_p1(
    const float* __restrict__ tf, const float* __restrict__ imp,
    const float* __restrict__ noise, unsigned* __restrict__ Et,
    unsigned* __restrict__ TFt)
{
    __shared__ float4 FD0[1168], FD1[1168];

    const int tid = threadIdx.x;
    const int bid = blockIdx.x;
    // XCD-chunked swizzle: each XCD covers contiguous (b, c0) -> L2 merging
    const int w  = ((bid & 7) << 10) | (bid >> 3);
    const int b  = w >> 9;
    const int c0 = (w & 511) << 3;

    // per-thread twiddles for the 5 fused (2x radix-2) DIF passes
    float2 tu0[5], tu1[5], tl[5];
    #pragma unroll
    for (int p = 0; p < 5; ++p) {
        const int lgU = 9 - 2 * p, lgL = lgU - 1, LL = 1 << lgL;
        const int j = tid & (LL - 1);
        const int iu0 = j << (9 - lgU), iu1 = (j + LL) << (9 - lgU), il = j << (9 - lgL);
        float s, c;
        __sincosf(-PI2 * (1.0f / 1024.0f) * (float)iu0, &s, &c); tu0[p] = make_float2(c, s);
        __sincosf(-PI2 * (1.0f / 1024.0f) * (float)iu1, &s, &c); tu1[p] = make_float2(c, s);
        __sincosf(-PI2 * (1.0f / 1024.0f) * (float)il,  &s, &c); tl[p]  = make_float2(c, s);
    }

    // env = clip(interp(imp),0,1)*noise for 8 cells
    {
        const float* ipr = imp + ((size_t)b * NCELLS + c0) * 16;
        float4 nz[8];
        #pragma unroll
        for (int cc = 0; cc < 8; ++cc)
            nz[cc] = *(const float4*)(noise + ((size_t)b * NCELLS + c0 + cc) * NFFT + 4 * tid);
        #pragma unroll
        for (int c = 0; c < 4; ++c) {
            int n = 4 * tid + c;
            float coord = (n + 0.5f) * (16.0f / 1024.0f) - 0.5f;
            coord = fminf(fmaxf(coord, 0.0f), 15.0f);
            int lo = (int)coord;
            int hi = lo + 1 > 15 ? 15 : lo + 1;
            float wl = coord - (float)lo, wh = 1.0f - wl;
            float e[8];
            #pragma unroll
            for (int cc = 0; cc < 8; ++cc)
                e[cc] = clip01(ipr[16 * cc + lo] * wh + ipr[16 * cc + hi] * wl) * f4c(nz[cc], c);
            FD0[IDX4(n)] = make_float4(e[0], e[1], e[2], e[3]);
            FD1[IDX4(n)] = make_float4(e[4], e[5], e[6], e[7]);
        }
    }
    __syncthreads();

    // forward FFT: 10 radix-2 DIF stages, fused 2/pass; both buffers per barrier
    #pragma unroll
    for (int p = 0; p < 5; ++p) {
        const int lgU = 9 - 2 * p, lgL = lgU - 1, LL = 1 << lgL;
        const int j = tid & (LL - 1), g = tid >> lgL;
        const int base = (g << (lgL + 2)) + j;
        const int q0 = IDX4(base), q1 = IDX4(base + LL);
        const int q2 = IDX4(base + 2 * LL), q3 = IDX4(base + 3 * LL);
        const float2 w0 = tu0[p], w1 = tu1[p], wl = tl[p];
        {
            float4 a0 = FD0[q0], a1 = FD0[q1], a2 = FD0[q2], a3 = FD0[q3];
            float4 u0 = f4add(a0, a2), d0 = f4sub(a0, a2);
            float4 u2 = cmul2(d0, w0);
            float4 u1 = f4add(a1, a3), d1 = f4sub(a1, a3);
            float4 u3 = cmul2(d1, w1);
            FD0[q0] = f4add(u0, u1);
            FD0[q1] = cmul2(f4sub(u0, u1), wl);
            FD0[q2] = f4add(u2, u3);
            FD0[q3] = cmul2(f4sub(u2, u3), wl);
        }
        {
            float4 a0 = FD1[q0], a1 = FD1[q1], a2 = FD1[q2], a3 = FD1[q3];
            float4 u0 = f4add(a0, a2), d0 = f4sub(a0, a2);
            float4 u2 = cmul2(d0, w0);
            float4 u1 = f4add(a1, a3), d1 = f4sub(a1, a3);
            float4 u3 = cmul2(d1, w1);
            FD1[q0] = f4add(u0, u1);
            FD1[q1] = cmul2(f4sub(u0, u1), wl);
            FD1[q2] = f4add(u2, u3);
            FD1[q3] = cmul2(f4sub(u2, u3), wl);
        }
        __syncthreads();
    }

    // extract: LINEAR slot read -> fp16 pack -> 16B coalesced store.
    // Et[b][slot][pair], pair = cell/2; this WG owns pairs c0/2 .. c0/2+3.
    #pragma unroll
    for (int it = 0; it < 4; ++it) {
        int s = tid + it * 256;
        float4 F0 = FD0[IDX4(s)], F1 = FD1[IDX4(s)];
        uint4 u = { pkh2(F0.x, F0.y), pkh2(F0.z, F0.w),
                    pkh2(F1.x, F1.y), pkh2(F1.z, F1.w) };
        *(uint4*)(Et + ((size_t)b * NFFT + s) * NPAIR + (c0 >> 1)) = u;
    }

    // tf: clip + pack bin pairs for 8 cells, two uint4 stores per kp
    {
        const float* r_[8];
        #pragma unroll
        for (int cc = 0; cc < 8; ++cc)
            r_[cc] = tf + ((size_t)b * NCELLS + c0 + cc) * NF;
        for (int kp = tid; kp < NKP; kp += 256) {
            bool hv = kp < 256;
            uint4 ua, ub;
            ua.x = pkh2(clip01(r_[0][2 * kp]), hv ? clip01(r_[0][2 * kp + 1]) : 0.0f);
            ua.y = pkh2(clip01(r_[1][2 * kp]), hv ? clip01(r_[1][2 * kp + 1]) : 0.0f);
            ua.z = pkh2(clip01(r_[2][2 * kp]), hv ? clip01(r_[2][2 * kp + 1]) : 0.0f);
            ua.w = pkh2(clip01(r_[3][2 * kp]), hv ? clip01(r_[3][2 * kp + 1]) : 0.0f);
            ub.x = pkh2(clip01(r_[4][2 * kp]), hv ? clip01(r_[4][2 * kp + 1]) : 0.0f);
            ub.y = pkh2(clip01(r_[5][2 * kp]), hv ? clip01(r_[5][2 * kp + 1]) : 0.0f);
            ub.z = pkh2(clip01(r_[6][2 * kp]), hv ? clip01(r_[6][2 * kp + 1]) : 0.0f);
            ub.w = pkh2(clip01(r_[7][2 * kp]), hv ? clip01(r_[7][2 * kp + 1]) : 0.0f);
            unsigned* dst = TFt + ((size_t)b * NKP + kp) * NCELLS + c0;
            *(uint4*)dst = ua;
            *(uint4*)(dst + 4) = ub;
        }
    }
}

// ---------------- P2 ----------------
// Grid 513, one WG per bin k. Thread q owns z-column of (x,y)=(q>>4,q&15)
// = cells q*16..q*16+15 = pairs q*8..q*8+7. Reads slot rows brev(k) and
// brev(1024-k), conj-split in registers. Box: z in regs, y/x via FP32
// float2 LDS ping-pong (Sz[0] y-stage, Sz[1] x-stage), 2 barriers/iter.
__global__ __launch_bounds__(256) void k_p2(
    const unsigned* __restrict__ Et, const unsigned* __restrict__ TFt,
    float2* __restrict__ ms)
{
    __shared__ float2 Sz[2][256 * 17];     // 69.6 KB -> 2 WG/CU

    const int q  = threadIdx.x;
    const int k  = blockIdx.x;
    const int kp = k >> 1, sel = k & 1;
    const int x  = q >> 4, y = q & 15;
    const int rA = __brev(k) >> 22;
    const int rB = __brev((1024 - k) & 1023) >> 22;

    float2 SF[16];
    #pragma unroll
    for (int z = 0; z < 16; ++z) SF[z] = make_float2(0.f, 0.f);

    uint4 FA[2][2], FB[2][2], TB[2][4];
    {
        const uint4* ea = (const uint4*)(Et + (size_t)rA * NPAIR + (q << 3));
        const uint4* eb = (const uint4*)(Et + (size_t)rB * NPAIR + (q << 3));
        const uint4* tp = (const uint4*)(TFt + (size_t)kp * NCELLS + (q << 4));
        FA[0][0] = ea[0]; FA[0][1] = ea[1];
        FB[0][0] = eb[0]; FB[0][1] = eb[1];
        TB[0][0] = tp[0]; TB[0][1] = tp[1]; TB[0][2] = tp[2]; TB[0][3] = tp[3];
    }

    #pragma unroll
    for (int b = 0; b < 16; ++b) {
        const int cur = b & 1, nxt = cur ^ 1;
        if (b + 1 < 16) {
            const uint4* ea = (const uint4*)(Et + ((size_t)(b + 1) * NFFT + rA) * NPAIR + (q << 3));
            const uint4* eb = (const uint4*)(Et + ((size_t)(b + 1) * NFFT + rB) * NPAIR + (q << 3));
            const uint4* tp = (const uint4*)(TFt + ((size_t)(b + 1) * NKP + kp) * NCELLS + (q << 4));
            FA[nxt][0] = ea[0]; FA[nxt][1] = ea[1];
            FB[nxt][0] = eb[0]; FB[nxt][1] = eb[1];
            TB[nxt][0] = tp[0]; TB[nxt][1] = tp[1]; TB[nxt][2] = tp[2]; TB[nxt][3] = tp[3];
        }

        // conj-split + T = r * (SF + E), per pair j (cells z=2j, 2j+1)
        float2 T[16];
        #pragma unroll
        for (int j = 0; j < 8; ++j) {
            unsigned fu = cmp4(FA[cur][j >> 2], j & 3);
            unsigned gu = cmp4(FB[cur][j >> 2], j & 3);
            float fr = h2lo(fu), fi = h2hi(fu);
            float gr = h2lo(gu), gi = h2hi(gu);
            float ear = 0.5f * (fr + gr), eai = 0.5f * (fi - gi);
            float ebr = 0.5f * (fi + gi), ebi = 0.5f * (gr - fr);
            unsigned te = cmp4(TB[cur][(2 * j) >> 2], (2 * j) & 3);
            unsigned to = cmp4(TB[cur][(2 * j + 1) >> 2], (2 * j + 1) & 3);
            float re_ = sel ? h2hi(te) : h2lo(te);
            float ro_ = sel ? h2hi(to) : h2lo(to);
            T[2 * j]     = make_float2(re_ * (SF[2 * j].x + ear),
                                       re_ * (SF[2 * j].y + eai));
            T[2 * j + 1] = make_float2(ro_ * (SF[2 * j + 1].x + ebr),
                                       ro_ * (SF[2 * j + 1].y + ebi));
        }
        if (q == MICQ) ms[b * NF + k] = T[8];

        // z-sum in place (rolling prev)
        {
            float2 p = make_float2(0.f, 0.f);
            #pragma unroll
            for (int z = 0; z < 16; ++z) {
                float2 c = T[z];
                float2 s = make_float2(c.x + p.x, c.y + p.y);
                if (z < 15) { s.x += T[z + 1].x; s.y += T[z + 1].y; }
                T[z] = s;
                p = c;
            }
        }

        // y-sum via LDS ping buffer (fp32)
        #pragma unroll
        for (int z = 0; z < 16; ++z) Sz[0][q * 17 + z] = T[z];
        __syncthreads();
        #pragma unroll
        for (int z = 0; z < 16; ++z) {
            float2 s = T[z];
            if (y > 0)  { float2 u = Sz[0][(q - 1) * 17 + z]; s.x += u.x; s.y += u.y; }
            if (y < 15) { float2 u = Sz[0][(q + 1) * 17 + z]; s.x += u.x; s.y += u.y; }
            T[z] = s;
            Sz[1][q * 17 + z] = s;
        }
        __syncthreads();
        // x-sum via LDS pong buffer
        #pragma unroll
        for (int z = 0; z < 16; ++z) {
            float2 s = T[z];
            if (x > 0)  { float2 u = Sz[1][(q - 16) * 17 + z]; s.x += u.x; s.y += u.y; }
            if (x < 15) { float2 u = Sz[1][(q + 16) * 17 + z]; s.x += u.x; s.y += u.y; }
            SF[z] = s;
        }
        // no trailing barrier: iter b+1's Sz[0] writes can't pass this iter's
        // bar2 (which all Sz[0] readers passed), and its Sz[1] writes come
        // after its own bar1, which all Sz[1] readers of this iter precede.
    }
}

// ---------------- P3 ----------------
__device__ __forceinline__ int pd(int i) { return i + (i >> 5); }

__global__ __launch_bounds__(256) void k_p3(
    const float2* __restrict__ ms, float* __restrict__ out)
{
    __shared__ float2 FD[1056];
    const int b = blockIdx.x, tid = threadIdx.x;

    for (int j = tid; j < NFFT; j += 256) {
        int jj = (j <= 512) ? j : 1024 - j;
        float2 v = ms[b * NF + jj];
        if (j > 512) v.y = -v.y;
        FD[pd(__brev(j) >> 22)] = v;
    }
    __syncthreads();

    for (int lg = 0; lg <= 9; ++lg) {
        const int len = 1 << lg;
        for (int pr = tid; pr < 512; pr += 256) {
            const int jj = pr & (len - 1);
            const int i0 = ((pr >> lg) << (lg + 1)) + jj;
            const int i1 = i0 + len;
            const int iw = jj << (9 - lg);
            float sn, cs;
            __sincosf(-PI2 * (1.0f / 1024.0f) * (float)iw, &sn, &cs);
            float2 a = FD[pd(i0)], bb = FD[pd(i1)];
            float tr = bb.x * cs + bb.y * sn;
            float ti = bb.y * cs - bb.x * sn;
            FD[pd(i0)] = make_float2(a.x + tr, a.y + ti);
            FD[pd(i1)] = make_float2(a.x - tr, a.y - ti);
        }
        __syncthreads();
    }
    for (int t = tid; t < NFFT; t += 256)
        out[b * NFFT + t] = FD[pd(t)].x * (1.0f / 1024.0f);
}

extern "C" void kernel_launch(void* const* d_in, const int* in_sizes, int n_in,
                              void* d_out, int out_size, void* d_ws, size_t ws_size,
                              hipStream_t stream)
{
    const float* tf    = (const float*)d_in[1];
    const float* imp   = (const float*)d_in[2];
    const float* noise = (const float*)d_in[3];
    float* out = (float*)d_out;

    unsigned* Et  = (unsigned*)d_ws;                              // 16*1024*2048 u32
    unsigned* TFt = Et + (size_t)16 * NFFT * NPAIR;               // 16*257*4096 u32
    float2*   ms  = (float2*)(TFt + (size_t)16 * NKP * NCELLS);   // 16*513 c64

    k_p1<<<8192, 256, 0, stream>>>(tf, imp, noise, Et, TFt);
    k_p2<<<NF, 256, 0, stream>>>(Et, TFt, ms);
    k_p3<<<16, 256, 0, stream>>>(ms, out);
}